// Round 10
// baseline (440.689 us; speedup 1.0000x reference)
//
#include <hip/hip_runtime.h>
#include <hip/hip_bf16.h>
#include <hip/hip_fp16.h>

#define DEVINL __device__ __forceinline__
typedef __hip_bfloat16 bf16;

typedef __attribute__((ext_vector_type(8))) __bf16 bf16x8;
typedef __attribute__((ext_vector_type(4))) float f32x4;

static constexpr int N_NODES  = 50000;
static constexpr int N_EDGES  = 800000;
static constexpr int N_GRAPHS = 128;
static constexpr float NEG_SLOPE = 0.2f;

// Dual-path input load: isbf=1 -> storage is bf16, else fp32.
DEVINL float ldIn(const void* __restrict__ p, size_t i, int isbf) {
    if (isbf) return __bfloat162float(((const bf16*)p)[i]);
    return ((const float*)p)[i];
}

DEVINL unsigned short f2bf(float f) {
    bf16 b = __float2bfloat16(f);
    return *reinterpret_cast<unsigned short*>(&b);
}

DEVINL float bfu2f(unsigned short u) {           // bf16 bits -> f32 (shift only)
    return __uint_as_float(((unsigned)u) << 16);
}

DEVINL unsigned f2hbits(float f) {
    __half h = __float2half(f);
    return (unsigned)*reinterpret_cast<unsigned short*>(&h);
}

DEVINL float hbits2f(unsigned bits) {
    unsigned short us = (unsigned short)bits;
    __half h = *reinterpret_cast<__half*>(&us);
    return __half2float(h);
}

DEVINL float lrelu_exp(float sc) {
    sc = sc > 0.f ? sc : NEG_SLOPE * sc;
    return __expf(sc);
}

// order-preserving float<->uint for atomicMax pooling (init cells to 0)
DEVINL unsigned fenc(float f) {
    unsigned s = __float_as_uint(f);
    return (s & 0x80000000u) ? ~s : (s | 0x80000000u);
}
DEVINL float fdec(unsigned u) {
    return (u & 0x80000000u) ? __uint_as_float(u ^ 0x80000000u) : __uint_as_float(~u);
}

template<int H>
DEVINL void ldrow(const unsigned short* __restrict__ p, unsigned short (&v)[H]) {
    if (H == 4) *reinterpret_cast<uint2*>(v)    = *reinterpret_cast<const uint2*>(p);
    else        *reinterpret_cast<unsigned*>(v) = *reinterpret_cast<const unsigned*>(p);
}

template<int H>
DEVINL float getse(const uint4& rv, int h) {
    unsigned bits;
    if (H == 4) {
        unsigned w16 = (h & 2) ? rv.z : rv.y;
        bits = (h & 1) ? (w16 >> 16) : (w16 & 0xffffu);
    } else {
        bits = h ? (rv.w >> 16) : (rv.w & 0xffffu);
    }
    return hbits2f(bits);
}

// ---------- runtime dtype detection (see round-1 notes) ----------
__global__ void detect_dtype_kernel(const unsigned short* __restrict__ xu,
                                    int* __restrict__ flag)
{
    int t = threadIdx.x;
    int bad = 0;
    for (int i = t; i < 1024; i += 64) {
        unsigned u = xu[2 * i];
        float v = __uint_as_float(u << 16);
        if (!(fabsf(v) <= 1e4f)) bad = 1;
    }
    unsigned long long m = __ballot(bad);
    if (t == 0) *flag = m ? 0 : 1;          // 1 = bf16 storage
}

// ---------- merged setup: M matrices (block 0) + both W-frag packs ----------
DEVINL void wfrag_one(const void* __restrict__ W, int isbf, bf16* __restrict__ Wfrag,
                      int idx, int K, int M)
{
    int KS = K / 32;
    int j    = idx & 7;
    int lane = (idx >> 3) & 63;
    int rem  = idx >> 9;
    int ks   = rem % KS;
    int ct   = rem / KS;
    int k = ks * 32 + (lane >> 4) * 8 + j;
    int n = ct * 16 + (lane & 15);
    Wfrag[idx] = __float2bfloat16(ldIn(W, (size_t)k * M + n, isbf));
}

__global__ void setup_kernel(const void* __restrict__ We1, const void* __restrict__ ae1,
                             const void* __restrict__ We2, const void* __restrict__ ae2,
                             const void* __restrict__ W1, const void* __restrict__ W2,
                             const int* __restrict__ flagp,
                             float* __restrict__ M1, float* __restrict__ M2,
                             bf16* __restrict__ wf1, bf16* __restrict__ wf2)
{
    const int isbf = *flagp;
    const int bx = blockIdx.x;
    if (bx == 0) {
        int t = threadIdx.x;
        if (t < 64) {
            int d = t >> 2, h = t & 3;
            float s = 0.f;
            for (int c = 0; c < 64; ++c)
                s += ldIn(We1, d * 256 + h * 64 + c, isbf) * ldIn(ae1, h * 64 + c, isbf);
            M1[d * 4 + h] = s;
        }
        if (t < 32) {
            int d = t >> 1, h = t & 1;
            float s = 0.f;
            for (int c = 0; c < 64; ++c)
                s += ldIn(We2, d * 128 + h * 64 + c, isbf) * ldIn(ae2, h * 64 + c, isbf);
            M2[d * 2 + h] = s;
        }
    } else if (bx <= 128) {
        wfrag_one(W1, isbf, wf1, (bx - 1) * 256 + threadIdx.x, 128, 256);
    } else {
        wfrag_one(W2, isbf, wf2, (bx - 129) * 256 + threadIdx.x, 256, 128);
    }
}

// ---------- MFMA GEMM + fused node-score epilogue ----------
template<int K, int M, int AMODE, int H>
__global__ __launch_bounds__(256)
void gemm_mfma_kernel(const void* __restrict__ A, const bf16* __restrict__ Wfrag,
                      bf16* __restrict__ C, const int* __restrict__ flagp, int N,
                      const void* __restrict__ a_src, const void* __restrict__ a_dst,
                      float* __restrict__ sA, float* __restrict__ sD)
{
    constexpr int KS = K / 32, CT = M / 16;
    constexpr int LDA = K + 8;
    __shared__ __align__(16) unsigned short Asm[64 * LDA];
    const int isbf = *flagp;
    const int tid  = threadIdx.x;
    const int wave = tid >> 6, lane = tid & 63;
    const int n0 = blockIdx.x * 64;

    for (int i = tid; i < 64 * (K / 8); i += 256) {
        int r  = i / (K / 8);
        int kc = (i % (K / 8)) * 8;
        int n  = n0 + r;
        unsigned short v[8] = {0, 0, 0, 0, 0, 0, 0, 0};
        if (n < N) {
            size_t base = (size_t)n * K + kc;
            if (AMODE == 1 || isbf) {
                *reinterpret_cast<uint4*>(v) =
                    *reinterpret_cast<const uint4*>((const unsigned short*)A + base);
            } else {
                const float* Af = (const float*)A + base;
                float4 f0 = *reinterpret_cast<const float4*>(Af);
                float4 f1 = *reinterpret_cast<const float4*>(Af + 4);
                v[0] = f2bf(f0.x); v[1] = f2bf(f0.y); v[2] = f2bf(f0.z); v[3] = f2bf(f0.w);
                v[4] = f2bf(f1.x); v[5] = f2bf(f1.y); v[6] = f2bf(f1.z); v[7] = f2bf(f1.w);
            }
        }
        *reinterpret_cast<uint4*>(&Asm[r * LDA + kc]) = *reinterpret_cast<uint4*>(v);
    }
    __syncthreads();

    f32x4 acc[CT];
    #pragma unroll
    for (int ct = 0; ct < CT; ++ct) acc[ct] = (f32x4){0.f, 0.f, 0.f, 0.f};

    const int arow  = wave * 16 + (lane & 15);
    const int akoff = (lane >> 4) * 8;
    #pragma unroll
    for (int ks = 0; ks < KS; ++ks) {
        bf16x8 af = *reinterpret_cast<const bf16x8*>(&Asm[arow * LDA + ks * 32 + akoff]);
        #pragma unroll
        for (int ct = 0; ct < CT; ++ct) {
            bf16x8 bfr = *reinterpret_cast<const bf16x8*>(
                &Wfrag[(((size_t)ct * KS + ks) * 64 + lane) * 8]);
            acc[ct] = __builtin_amdgcn_mfma_f32_16x16x32_bf16(af, bfr, acc[ct], 0, 0, 0);
        }
    }

    const int crow0 = n0 + wave * 16 + (lane >> 4) * 4;
    const int ccol  = lane & 15;
    #pragma unroll
    for (int ct = 0; ct < CT; ++ct) {
        #pragma unroll
        for (int r = 0; r < 4; ++r) {
            int row = crow0 + r;
            if (row < N) C[(size_t)row * M + ct * 16 + ccol] = __float2bfloat16(acc[ct][r]);
        }
    }

    // ---- fused attention logits ----
    float psA[4][H], psD[4][H];
    #pragma unroll
    for (int r = 0; r < 4; ++r)
        #pragma unroll
        for (int hh = 0; hh < H; ++hh) { psA[r][hh] = 0.f; psD[r][hh] = 0.f; }
    #pragma unroll
    for (int ct = 0; ct < CT; ++ct) {
        float as = ldIn(a_src, ct * 16 + ccol, isbf);
        float ad = ldIn(a_dst, ct * 16 + ccol, isbf);
        const int hh = ct >> 2;
        #pragma unroll
        for (int r = 0; r < 4; ++r) {
            psA[r][hh] += acc[ct][r] * as;
            psD[r][hh] += acc[ct][r] * ad;
        }
    }
    #pragma unroll
    for (int m = 1; m < 16; m <<= 1) {
        #pragma unroll
        for (int r = 0; r < 4; ++r)
            #pragma unroll
            for (int hh = 0; hh < H; ++hh) {
                psA[r][hh] += __shfl_xor(psA[r][hh], m);
                psD[r][hh] += __shfl_xor(psD[r][hh], m);
            }
    }
    if (ccol == 0) {
        #pragma unroll
        for (int r = 0; r < 4; ++r) {
            int row = crow0 + r;
            if (row < N) {
                #pragma unroll
                for (int hh = 0; hh < H; ++hh) {
                    sA[(size_t)row * H + hh] = psA[r][hh];
                    sD[(size_t)row * H + hh] = psD[r][hh];
                }
            }
        }
    }
}

// ---------- CSR build: count + per-edge stable rank (atomic return) ----------
__global__ void csr_count_kernel(const int* __restrict__ dst, int* __restrict__ cnt,
                                 int* __restrict__ rank)
{
    int e = blockIdx.x * blockDim.x + threadIdx.x;
    if (e >= N_EDGES) return;
    rank[e] = atomicAdd(&cnt[dst[e]], 1);
}

__global__ __launch_bounds__(256)
void scan_sum_kernel(const int* __restrict__ cnt, int* __restrict__ bsum)
{
    __shared__ int sm[256];
    int i = blockIdx.x * 256 + threadIdx.x;
    sm[threadIdx.x] = (i < N_NODES) ? cnt[i] : 0;
    __syncthreads();
    for (int off = 128; off; off >>= 1) {
        if (threadIdx.x < off) sm[threadIdx.x] += sm[threadIdx.x + off];
        __syncthreads();
    }
    if (threadIdx.x == 0) bsum[blockIdx.x] = sm[0];
}

__global__ __launch_bounds__(256)
void scan_off_kernel(int* __restrict__ bsum, int nb)
{
    __shared__ int sm[256];
    int tid = threadIdx.x;
    int v = (tid < nb) ? bsum[tid] : 0;
    sm[tid] = v;
    __syncthreads();
    for (int off = 1; off < 256; off <<= 1) {
        int t = (tid >= off) ? sm[tid - off] : 0;
        __syncthreads();
        sm[tid] += t;
        __syncthreads();
    }
    if (tid < nb) bsum[tid] = sm[tid] - v;
}

__global__ __launch_bounds__(256)
void scan_final_kernel(const int* __restrict__ cnt, const int* __restrict__ bsum,
                       int* __restrict__ row)
{
    __shared__ int sm[256];
    int i = blockIdx.x * 256 + threadIdx.x;
    int tid = threadIdx.x;
    int v = (i < N_NODES) ? cnt[i] : 0;
    sm[tid] = v;
    __syncthreads();
    for (int off = 1; off < 256; off <<= 1) {
        int t = (tid >= off) ? sm[tid - off] : 0;
        __syncthreads();
        sm[tid] += t;
        __syncthreads();
    }
    int excl = sm[tid] - v + bsum[blockIdx.x];
    if (i < N_NODES) row[i] = excl;
    if (i == N_NODES - 1) row[N_NODES] = excl + v;
}

// ---------- scatter (atomic-free): pos = row[d] + rank[e]; one 16-B record ----------
__global__ void csr_scatter_kernel(const int* __restrict__ srcI, const int* __restrict__ dstI,
                                   const void* __restrict__ eattr, const int* __restrict__ flagp,
                                   const float* __restrict__ M1, const float* __restrict__ M2,
                                   const int* __restrict__ row, const int* __restrict__ rank,
                                   uint4* __restrict__ erec)
{
    const int isbf = *flagp;
    int e = blockIdx.x * blockDim.x + threadIdx.x;
    if (e >= N_EDGES) return;
    float attr[16];
    #pragma unroll
    for (int k = 0; k < 16; ++k) attr[k] = ldIn(eattr, (size_t)e * 16 + k, isbf);
    float4 o1 = {0.f, 0.f, 0.f, 0.f};
    float2 o2 = {0.f, 0.f};
    #pragma unroll
    for (int k = 0; k < 16; ++k) {
        o1.x += attr[k] * M1[k * 4 + 0];
        o1.y += attr[k] * M1[k * 4 + 1];
        o1.z += attr[k] * M1[k * 4 + 2];
        o1.w += attr[k] * M1[k * 4 + 3];
        o2.x += attr[k] * M2[k * 2 + 0];
        o2.y += attr[k] * M2[k * 2 + 1];
    }
    int pos = row[dstI[e]] + rank[e];
    uint4 rec;
    rec.x = (unsigned)srcI[e];
    rec.y = f2hbits(o1.x) | (f2hbits(o1.y) << 16);
    rec.z = f2hbits(o1.z) | (f2hbits(o1.w) << 16);
    rec.w = f2hbits(o2.x) | (f2hbits(o2.y) << 16);
    erec[pos] = rec;
}

// ---------- fused score+softmax+aggregate (round-8 form: 1 edge/wave, unroll 8) ----
// w_j = exp(leaky(sA[s_j] + sD[d] + se[j])); self-loop from seSum/cnt (linearity).
// LAYER 1 (H=4): out = relu(agg + b1) -> bf16 h1[N,256]
// LAYER 2 (H=2): out = atomicMax-pooled mean_heads(agg)+b2 -> encoded uint gpool
template<int H, int LAYER>
__global__ __launch_bounds__(256)
void agg_fused_kernel(const int* __restrict__ row, const uint4* __restrict__ erec,
                      const bf16* __restrict__ xs,
                      const float* __restrict__ sA, const float* __restrict__ sD,
                      const void* __restrict__ bias, const int* __restrict__ batch,
                      const int* __restrict__ flagp, void* __restrict__ out)
{
    const int isbf = *flagp;
    int dv = (blockIdx.x * 256 + threadIdx.x) >> 6;
    const int d = __builtin_amdgcn_readfirstlane(dv);   // wave-uniform -> scalar loads
    const int lane = threadIdx.x & 63;
    if (d >= N_NODES) return;
    const int h = (lane * H) >> 6;                      // this lane's head
    const unsigned short* xsu = (const unsigned short*)xs;
    const float sDv = sD[(size_t)d * H + h];
    const float sAd = sA[(size_t)d * H + h];

    float acc[H];
    #pragma unroll
    for (int i = 0; i < H; ++i) acc[i] = 0.f;
    float den = 0.f, seSum = 0.f;

    const int b = row[d], eend = row[d + 1];
    int j = b;
    for (; j + 7 < eend; j += 8) {
        int s[8];
        float se[8], sa[8];
        unsigned short v[8][H];
        uint4 rv[8];
        #pragma unroll
        for (int u = 0; u < 8; ++u) rv[u] = erec[j + u];
        #pragma unroll
        for (int u = 0; u < 8; ++u) s[u] = (int)rv[u].x;
        #pragma unroll
        for (int u = 0; u < 8; ++u) ldrow<H>(&xsu[(size_t)s[u] * (H * 64) + lane * H], v[u]);
        #pragma unroll
        for (int u = 0; u < 8; ++u) sa[u] = sA[(size_t)s[u] * H + h];
        #pragma unroll
        for (int u = 0; u < 8; ++u) se[u] = getse<H>(rv[u], h);
        #pragma unroll
        for (int u = 0; u < 8; ++u) {
            float w = lrelu_exp(sa[u] + sDv + se[u]);
            seSum += se[u];
            den += w;
            #pragma unroll
            for (int i = 0; i < H; ++i) acc[i] += w * bfu2f(v[u][i]);
        }
    }
    for (; j < eend; ++j) {
        uint4 rv = erec[j];
        const int s = (int)rv.x;
        float se = getse<H>(rv, h);
        const float sa = sA[(size_t)s * H + h];
        unsigned short v[H];
        ldrow<H>(&xsu[(size_t)s * (H * 64) + lane * H], v);
        const float w = lrelu_exp(sa + sDv + se);
        seSum += se;
        den += w;
        #pragma unroll
        for (int i = 0; i < H; ++i) acc[i] += w * bfu2f(v[i]);
    }

    // self loop: attr = mean of incident edge attrs -> se_self = seSum/cnt
    {
        const int cntv = eend - b;
        const float seM = seSum / fmaxf((float)cntv, 1.f);
        const float wS = lrelu_exp(sAd + sDv + seM);
        unsigned short v[H];
        ldrow<H>(&xsu[(size_t)d * (H * 64) + lane * H], v);
        den += wS;
        #pragma unroll
        for (int i = 0; i < H; ++i) acc[i] += wS * bfu2f(v[i]);
    }

    const float rden = 1.f / (den + 1e-16f);
    if (LAYER == 1) {
        unsigned short o[H];
        #pragma unroll
        for (int i = 0; i < H; ++i) {
            float v = acc[i] * rden + ldIn(bias, lane * H + i, isbf);
            o[i] = f2bf(v > 0.f ? v : 0.f);
        }
        *reinterpret_cast<uint2*>(&((unsigned short*)out)[(size_t)d * (H * 64) + lane * H]) =
            *reinterpret_cast<uint2*>(o);
    } else {
        // lane (<32): channels {2*lane, 2*lane+1} head0; lane+32 same channels head1
        float v0 = acc[0] * rden, v1 = acc[1] * rden;
        float p0 = __shfl(v0, lane + 32), p1 = __shfl(v1, lane + 32);
        if (lane < 32) {
            const int g = batch[d];
            float o0 = 0.5f * (v0 + p0) + ldIn(bias, lane * 2 + 0, isbf);
            float o1 = 0.5f * (v1 + p1) + ldIn(bias, lane * 2 + 1, isbf);
            unsigned* gp = (unsigned*)out;
            atomicMax(&gp[g * 64 + lane * 2 + 0], fenc(o0));
            atomicMax(&gp[g * 64 + lane * 2 + 1], fenc(o1));
        }
    }
}

// ---------- readout: decode pooled max, dot with Wr ----------
__global__ void readout_kernel(const unsigned* __restrict__ gpool, const void* __restrict__ Wr,
                               const void* __restrict__ br, const int* __restrict__ flagp,
                               void* __restrict__ out)
{
    const int isbf = *flagp;
    int gi = blockIdx.x;
    int lane = threadIdx.x;
    float p = fdec(gpool[gi * 64 + lane]) * ldIn(Wr, lane, isbf);
    for (int off = 32; off; off >>= 1) p += __shfl_down(p, off);
    if (lane == 0) {
        float r = p + ldIn(br, 0, isbf);
        if (isbf) ((bf16*)out)[gi] = __float2bfloat16(r);
        else      ((float*)out)[gi] = r;
    }
}

extern "C" void kernel_launch(void* const* d_in, const int* in_sizes, int n_in,
                              void* d_out, int out_size, void* d_ws, size_t ws_size,
                              hipStream_t stream)
{
    const void* x     = d_in[0];
    const void* ea    = d_in[1];
    const int*  eidx  = (const int*)d_in[2];
    const int*  batch = (const int*)d_in[3];
    const void* W1  = d_in[4];
    const void* as1 = d_in[5];
    const void* ad1 = d_in[6];
    const void* We1 = d_in[7];
    const void* ae1 = d_in[8];
    const void* b1  = d_in[9];
    const void* W2  = d_in[10];
    const void* as2 = d_in[11];
    const void* ad2 = d_in[12];
    const void* We2 = d_in[13];
    const void* ae2 = d_in[14];
    const void* b2  = d_in[15];
    const void* Wr  = d_in[16];
    const void* br  = d_in[17];

    const int* srcI = eidx;
    const int* dstI = eidx + N_EDGES;

    // ---- workspace layout (float-index offsets), peak ~70 MB ----
    float*    ws    = (float*)d_ws;
    bf16*     xs    = (bf16*)ws;                     // [0, 6.4M): N*256 bf16 (L2: N*128)
    bf16*     h1    = (bf16*)(ws + 6400000);         // N*256 bf16 -> [6.4M, 12.8M)
    uint4*    erec  = (uint4*)(ws + 12800000);       // E 16-B records -> [12.8M, 16M)
    float*    sA1   = ws + 16000000;                 // N*4
    float*    sD1   = ws + 16200000;                 // N*4
    float*    sA2   = ws + 16400000;                 // N*2
    float*    sD2   = ws + 16500000;                 // N*2
    int*      ib    = (int*)(ws + 16600000);
    int*      row    = ib;                           // N+1 (pad 50016)
    int*      cnt    = ib + 50016;                   // N (pad 50016)
    int*      bsum   = ib + 100032;                  // 256 (pad 352)
    int*      rank   = ib + 100384;                  // E
    float*    misc  = ws + 16600000 + 900384;
    int*      flag  = (int*)misc;                    // 1
    float*    M1    = misc + 16;                     // 64
    float*    M2    = misc + 80;                     // 32
    unsigned* gpool = (unsigned*)(misc + 112);       // 128*64 encoded
    bf16*     wf1   = (bf16*)(misc + 8320);          // 32768 bf16
    bf16*     wf2   = (bf16*)(misc + 8320 + 16384);  // 32768 bf16

    hipMemsetAsync(cnt, 0, N_NODES * sizeof(int), stream);
    hipMemsetAsync(gpool, 0, N_GRAPHS * 64 * sizeof(unsigned), stream);

    detect_dtype_kernel<<<1, 64, 0, stream>>>((const unsigned short*)x, flag);
    setup_kernel<<<257, 256, 0, stream>>>(We1, ae1, We2, ae2, W1, W2, flag, M1, M2, wf1, wf2);

    // ----- CSR over dst (parallel scan) + atomic-free packed-record scatter -----
    const int NB = (N_NODES + 255) / 256;         // 196
    csr_count_kernel<<<(N_EDGES + 255) / 256, 256, 0, stream>>>(dstI, cnt, rank);
    scan_sum_kernel<<<NB, 256, 0, stream>>>(cnt, bsum);
    scan_off_kernel<<<1, 256, 0, stream>>>(bsum, NB);
    scan_final_kernel<<<NB, 256, 0, stream>>>(cnt, bsum, row);
    csr_scatter_kernel<<<(N_EDGES + 255) / 256, 256, 0, stream>>>(
        srcI, dstI, ea, flag, M1, M2, row, rank, erec);

    const int GB = (N_NODES + 63) / 64;           // 782 row-blocks

    // ----- layer 1 (H=4, concat); node scores fused into GEMM epilogue -----
    gemm_mfma_kernel<128, 256, 0, 4><<<GB, 256, 0, stream>>>(
        x, wf1, xs, flag, N_NODES, as1, ad1, sA1, sD1);
    agg_fused_kernel<4, 1><<<(N_NODES + 3) / 4, 256, 0, stream>>>(
        row, erec, xs, sA1, sD1, b1, batch, flag, h1);

    // ----- layer 2 (H=2, mean); max-pool fused via encoded atomicMax -----
    gemm_mfma_kernel<256, 128, 1, 2><<<GB, 256, 0, stream>>>(
        h1, wf2, xs, flag, N_NODES, as2, ad2, sA2, sD2);
    agg_fused_kernel<2, 2><<<(N_NODES + 3) / 4, 256, 0, stream>>>(
        row, erec, xs, sA2, sD2, b2, batch, flag, gpool);

    // ----- readout -----
    readout_kernel<<<N_GRAPHS, 64, 0, stream>>>(gpool, Wr, br, flag, d_out);
}